// Round 10
// baseline (328.321 us; speedup 1.0000x reference)
//
#include <hip/hip_runtime.h>

#define N_NODES 50000
#define N_EDGES 800000
#define NUM_GRAPHS 64

// Fixed-capacity CSR: deg ~ Poisson(16); P(deg>64) ~ 1e-18. Capacity 64 u16
// slots per node removes histogram+scan; cursor[n]-n*64 IS the degree.
#define CAPLOG 6
#define CAP    (1 << CAPLOG)

__device__ __forceinline__ float bf_lo(unsigned u) { return __uint_as_float(u << 16); }
__device__ __forceinline__ float bf_hi(unsigned u) { return __uint_as_float(u & 0xffff0000u); }
__device__ __forceinline__ unsigned short f2bf(float f) {           // RNE
    unsigned u = __float_as_uint(f);
    return (unsigned short)((u + 0x7fffu + ((u >> 16) & 1u)) >> 16);
}

// ---------------- cursor init: cursor[n] = n*CAP ----------------------------
__global__ void k_initcur(int* __restrict__ cursor) {
    int i = blockIdx.x * blockDim.x + threadIdx.x;
    if (i < N_NODES) cursor[i] = i << CAPLOG;
}

// ---------------- XCD-local CSR scatter + graph bounds -----------------------
// r5-r8: random cross-XCD 2B stores bounce csr lines; node-range grouping by
// blockIdx%8 keeps each csr line's writers on one XCD. Device-scope atomics
// don't benefit from locality (common coherence point) - they're the floor.
#define SC_BPG   128
#define SC_GRID  (8 * SC_BPG)
#define NPG      ((N_NODES + 7) / 8)
__global__ __launch_bounds__(256) void k_scatter_xcd(
        const int* __restrict__ ei, int* __restrict__ cursor,
        unsigned short* __restrict__ csr,
        const int* __restrict__ batch, int* __restrict__ start) {
    if (blockIdx.x == SC_GRID) {
        int t = threadIdx.x;
        if (t <= NUM_GRAPHS) {
            int lo = 0, hi = N_NODES;
            while (lo < hi) {
                int mid = (lo + hi) >> 1;
                if (batch[mid] < t) lo = mid + 1; else hi = mid;
            }
            start[t] = lo;
        }
        return;
    }
    const int g  = blockIdx.x & 7;
    const int b  = blockIdx.x >> 3;
    const int lo = g * NPG, hi = lo + NPG;
    const int* __restrict__ dst = ei + N_EDGES;
    for (int e = b * 256 + threadIdx.x; e < N_EDGES; e += 256 * SC_BPG) {
        int d = dst[e];
        if (d >= lo && d < hi) {
            int p = atomicAdd(&cursor[d], 1);
            if (p < ((d + 1) << CAPLOG)) csr[p] = (unsigned short)ei[e];
        }
    }
}

// ---------------- GEMM: H = (X @ W) * dinv, bf16 PLANE-layout output --------
// W tile in LDS only (r5: LDS X-transpose = 1.24e7 bank-conflict cycles).
// Output planes: feature f -> plane f/PW (plane = N_NODES x PW bf16 = 64B or
// 32B rows). Planes make the next agg's per-XCD gather footprint <= 3.2MB
// (L2-resident) instead of 6.4-9.6MB (L2-thrash -> L3 latency).
template <int K, int M, int MT, int FTH, int NTH, int NT, int PW>
__global__ __launch_bounds__(FTH * NTH)
void k_gemm(const float* __restrict__ X, const float* __restrict__ W,
            const int* __restrict__ cursor, unsigned short* __restrict__ H) {
    constexpr int BLOCK = FTH * NTH;
    __shared__ float ws[K * MT];
    const int tid = threadIdx.x;
    const int n0 = blockIdx.x * (NTH * NT);
    const int c0 = blockIdx.y * MT;

    for (int i = tid; i < K * MT / 4; i += BLOCK) {
        int k = i / (MT / 4), cv = i % (MT / 4);
        *(float4*)&ws[k * MT + cv * 4] = *(const float4*)&W[k * M + c0 + cv * 4];
    }
    __syncthreads();

    const int ft = tid % FTH;
    const int nt = tid / FTH;
    const float* xp[NT];
    #pragma unroll
    for (int i = 0; i < NT; ++i) {
        int node = n0 + nt * NT + i;
        int nc = node < N_NODES ? node : N_NODES - 1;   // clamp; store is guarded
        xp[i] = X + (size_t)nc * K;
    }
    float acc[NT][4];
    #pragma unroll
    for (int i = 0; i < NT; ++i) { acc[i][0] = acc[i][1] = acc[i][2] = acc[i][3] = 0.f; }

    for (int k = 0; k < K; k += 4) {
        float4 w0 = *(const float4*)&ws[(k + 0) * MT + ft * 4];
        float4 w1 = *(const float4*)&ws[(k + 1) * MT + ft * 4];
        float4 w2 = *(const float4*)&ws[(k + 2) * MT + ft * 4];
        float4 w3 = *(const float4*)&ws[(k + 3) * MT + ft * 4];
        #pragma unroll
        for (int i = 0; i < NT; ++i) {
            float4 xv = *(const float4*)(xp[i] + k);
            acc[i][0] += xv.x * w0.x + xv.y * w1.x + xv.z * w2.x + xv.w * w3.x;
            acc[i][1] += xv.x * w0.y + xv.y * w1.y + xv.z * w2.y + xv.w * w3.y;
            acc[i][2] += xv.x * w0.z + xv.y * w1.z + xv.z * w2.z + xv.w * w3.z;
            acc[i][3] += xv.x * w0.w + xv.y * w1.w + xv.z * w2.w + xv.w * w3.w;
        }
    }
    const int f0 = c0 + ft * 4;
    const int pl = f0 / PW, fin = f0 % PW;
    unsigned short* Hp = H + (size_t)pl * N_NODES * PW + fin;
    #pragma unroll
    for (int i = 0; i < NT; ++i) {
        int node = n0 + nt * NT + i;
        if (node < N_NODES) {
            int deg = cursor[node] - (node << CAPLOG);
            float s = rsqrtf((float)(deg + 1));
            ushort4 o;
            o.x = f2bf(acc[i][0] * s); o.y = f2bf(acc[i][1] * s);
            o.z = f2bf(acc[i][2] * s); o.w = f2bf(acc[i][3] * s);
            *(ushort4*)&Hp[(size_t)node * PW] = o;
        }
    }
}

// ---------------- plane-partitioned pull aggregation -------------------------
// Blocks are pinned to planes via the blockIdx%8 XCD round-robin heuristic:
// cls[g] gives the plane XCD g serves, so XCD g's random gathers touch ONLY
// its own <=3.2MB plane -> L2-resident (~200cy) instead of L3 (~600cy).
// Wrong %8 mapping only degrades to status quo (correctness unaffected).
template <int F, int PW, int NBP>
__global__ __launch_bounds__(256)
void k_agg_pl(const unsigned short* __restrict__ H, const int* __restrict__ cursor,
              const unsigned short* __restrict__ csr,
              const float* __restrict__ bias, float* __restrict__ OUT) {
    constexpr int CPP = PW / 8;                 // 16B chunks per plane row
    const int cls[8] = {0, 0, 0, 1, 1, 2, 2, 2};
    const int rnk[8] = {0, 1, 2, 0, 1, 0, 1, 2};
    const int npx[3] = {3, 2, 3};
    const int g = blockIdx.x & 7;
    const int j = blockIdx.x >> 3;
    const int p = cls[g];
    const int w = j * npx[p] + rnk[g];
    if (w >= NBP) return;
    int item = w * 256 + threadIdx.x;
    int node = item / CPP, cw = item % CPP;
    if (node >= N_NODES) return;

    int c1 = cursor[node];
    int e0 = node << CAPLOG;
    int e1 = min(c1, e0 + CAP);
    float d = rsqrtf((float)(c1 - e0 + 1));
    const unsigned short* Hp = H + (size_t)p * N_NODES * PW + cw * 8;
    uint4 sv = *(const uint4*)(Hp + (size_t)node * PW);       // self loop
    float a0 = bf_lo(sv.x), a1 = bf_hi(sv.x), a2 = bf_lo(sv.y), a3 = bf_hi(sv.y);
    float a4 = bf_lo(sv.z), a5 = bf_hi(sv.z), a6 = bf_lo(sv.w), a7 = bf_hi(sv.w);
    for (int e = e0; e < e1; ++e) {
        int s = csr[e];
        uint4 v = *(const uint4*)(Hp + (size_t)s * PW);
        a0 += bf_lo(v.x); a1 += bf_hi(v.x);
        a2 += bf_lo(v.y); a3 += bf_hi(v.y);
        a4 += bf_lo(v.z); a5 += bf_hi(v.z);
        a6 += bf_lo(v.w); a7 += bf_hi(v.w);
    }
    const int f = p * PW + cw * 8;
    const float4* bp = (const float4*)(bias + f);
    float4 b0 = bp[0], b1 = bp[1];
    float4 o0, o1;
    o0.x = fmaxf(a0 * d + b0.x, 0.f); o0.y = fmaxf(a1 * d + b0.y, 0.f);
    o0.z = fmaxf(a2 * d + b0.z, 0.f); o0.w = fmaxf(a3 * d + b0.w, 0.f);
    o1.x = fmaxf(a4 * d + b1.x, 0.f); o1.y = fmaxf(a5 * d + b1.y, 0.f);
    o1.z = fmaxf(a6 * d + b1.z, 0.f); o1.w = fmaxf(a7 * d + b1.w, 0.f);
    float* op = OUT + (size_t)node * F + f;
    *(float4*)op = o0;
    *(float4*)(op + 4) = o1;
}

// ---------------- layer-3 aggregation (single 3.2MB plane, already L2-sized) -
template <int F, int STRIDE>
__global__ void k_agg_bf(const unsigned short* __restrict__ H, const int* __restrict__ cursor,
                         const unsigned short* __restrict__ csr,
                         const float* __restrict__ bias, float* __restrict__ OUT) {
    constexpr int FV = F / 8;
    int t = blockIdx.x * blockDim.x + threadIdx.x;
    int node = t / FV, c = t % FV;
    if (node >= N_NODES) return;
    int c1 = cursor[node];
    int e0 = node << CAPLOG;
    int e1 = min(c1, e0 + CAP);
    float d = rsqrtf((float)(c1 - e0 + 1));
    const unsigned short* Hc = H + c * 8;
    uint4 sv = *(const uint4*)(Hc + (size_t)node * STRIDE);   // self loop
    float a0 = bf_lo(sv.x), a1 = bf_hi(sv.x), a2 = bf_lo(sv.y), a3 = bf_hi(sv.y);
    float a4 = bf_lo(sv.z), a5 = bf_hi(sv.z), a6 = bf_lo(sv.w), a7 = bf_hi(sv.w);
    for (int e = e0; e < e1; ++e) {
        int s = csr[e];
        uint4 v = *(const uint4*)(Hc + (size_t)s * STRIDE);
        a0 += bf_lo(v.x); a1 += bf_hi(v.x);
        a2 += bf_lo(v.y); a3 += bf_hi(v.y);
        a4 += bf_lo(v.z); a5 += bf_hi(v.z);
        a6 += bf_lo(v.w); a7 += bf_hi(v.w);
    }
    const float4* bp = (const float4*)(bias + c * 8);
    float4 b0 = bp[0], b1 = bp[1];
    float4 o0, o1;
    o0.x = fmaxf(a0 * d + b0.x, 0.f); o0.y = fmaxf(a1 * d + b0.y, 0.f);
    o0.z = fmaxf(a2 * d + b0.z, 0.f); o0.w = fmaxf(a3 * d + b0.w, 0.f);
    o1.x = fmaxf(a4 * d + b1.x, 0.f); o1.y = fmaxf(a5 * d + b1.y, 0.f);
    o1.z = fmaxf(a6 * d + b1.z, 0.f); o1.w = fmaxf(a7 * d + b1.w, 0.f);
    float* op = OUT + (size_t)node * F + c * 8;
    *(float4*)op = o0;
    *(float4*)(op + 4) = o1;
}

// ---------------- mean-pool per graph (batch sorted -> contiguous ranges) ----
__global__ __launch_bounds__(256) void k_pool(const float* __restrict__ H,
                                              const int* __restrict__ start,
                                              float* __restrict__ out) {
    __shared__ float red[256];
    const int g = blockIdx.x;
    const int c = threadIdx.x & 31;
    const int r0 = threadIdx.x >> 5;          // 0..7
    const int lo = start[g], hi = start[g + 1];
    float acc = 0.f;
    for (int r = lo + r0; r < hi; r += 8)
        acc += H[(size_t)r * 32 + c];
    red[threadIdx.x] = acc;
    __syncthreads();
    if (threadIdx.x < 128) red[threadIdx.x] += red[threadIdx.x + 128];
    __syncthreads();
    if (threadIdx.x < 64) red[threadIdx.x] += red[threadIdx.x + 64];
    __syncthreads();
    if (threadIdx.x < 32) {
        float s = red[threadIdx.x] + red[threadIdx.x + 32];
        float cnt = fmaxf((float)(hi - lo), 1.0f);
        out[g * 32 + c] = s / cnt;
    }
}

extern "C" void kernel_launch(void* const* d_in, const int* in_sizes, int n_in,
                              void* d_out, int out_size, void* d_ws, size_t ws_size,
                              hipStream_t stream) {
    const float* x     = (const float*)d_in[0];
    const int*   ei    = (const int*)d_in[1];
    const int*   batch = (const int*)d_in[2];
    const float* W1    = (const float*)d_in[3];
    const float* b1    = (const float*)d_in[4];
    const float* W2    = (const float*)d_in[5];
    const float* b2    = (const float*)d_in[6];
    const float* W3    = (const float*)d_in[7];
    const float* b3    = (const float*)d_in[8];
    float* out = (float*)d_out;

    char* ws = (char*)d_ws;
    size_t o = 0;
    auto alloc = [&](size_t bytes) {
        char* p = ws + o;
        o = (o + bytes + 255) & ~(size_t)255;
        return p;
    };
    // P1: fp32 O1 [50000x96] -> later fp32 O3 [50000x32]
    // P2: bf16 H1 planes 3x[50000x32] (9.6MB) -> later fp32 O2 [50000x48]
    // P3: bf16 H2 planes 3x[50000x16] (4.8MB) -> later bf16 H3 [50000x32]
    float* P1 = (float*)alloc((size_t)N_NODES * 96 * 4);
    char*  P2 = (char*) alloc((size_t)N_NODES * 96 * 2);   // == 48*4
    char*  P3 = (char*) alloc((size_t)N_NODES * 64 * 2);
    int*   cursor = (int*)alloc((size_t)N_NODES * 4);
    unsigned short* csr = (unsigned short*)alloc((size_t)N_NODES * CAP * 2);  // 6.4MB
    int*   start  = (int*)alloc((NUM_GRAPHS + 1) * 4);

    unsigned short* H1 = (unsigned short*)P2;   // bf16 planes, PW=32
    float*          O1 = P1;                    // fp32, stride 96
    unsigned short* H2 = (unsigned short*)P3;   // bf16 planes, PW=16
    float*          O2 = (float*)P2;            // fp32, stride 48
    unsigned short* H3 = (unsigned short*)P3;   // bf16, single plane PW=32
    float*          O3 = P1;                    // fp32, stride 32

    // fixed-capacity CSR build (no histogram / no scan)
    hipLaunchKernelGGL(k_initcur, dim3((N_NODES + 255) / 256), dim3(256), 0, stream, cursor);
    hipLaunchKernelGGL(k_scatter_xcd, dim3(SC_GRID + 1), dim3(256), 0, stream, ei, cursor, csr, batch, start);

    // layer 1: K=128 -> M=96, H1 in 3 planes of 32 feats
    hipLaunchKernelGGL((k_gemm<128, 96, 48, 12, 16, 4, 32>), dim3((N_NODES + 63) / 64, 2), dim3(192), 0, stream,
                       x, W1, cursor, H1);
    // NBP1 = ceil(50000*4/256) = 782; grid = 8 * ceil(782/min|S|=2) = 8*391
    hipLaunchKernelGGL((k_agg_pl<96, 32, 782>), dim3(8 * 391), dim3(256), 0, stream,
                       H1, cursor, csr, b1, O1);
    // layer 2: K=96 -> M=48, H2 in 3 planes of 16 feats
    hipLaunchKernelGGL((k_gemm<96, 48, 48, 12, 16, 4, 16>), dim3((N_NODES + 63) / 64, 1), dim3(192), 0, stream,
                       O1, W2, cursor, H2);
    // NBP2 = ceil(50000*2/256) = 391; grid = 8 * ceil(391/2) = 8*196
    hipLaunchKernelGGL((k_agg_pl<48, 16, 391>), dim3(8 * 196), dim3(256), 0, stream,
                       H2, cursor, csr, b2, O2);
    // layer 3: K=48 -> M=32, single 3.2MB plane (already L2-sized per XCD)
    hipLaunchKernelGGL((k_gemm<48, 32, 32, 8, 24, 4, 32>), dim3((N_NODES + 95) / 96, 1), dim3(192), 0, stream,
                       O2, W3, cursor, H3);
    hipLaunchKernelGGL((k_agg_bf<32, 32>), dim3((N_NODES * 4 + 255) / 256), dim3(256), 0, stream,
                       H3, cursor, csr, b3, O3);
    // mean pool over contiguous per-graph node ranges
    hipLaunchKernelGGL(k_pool, dim3(NUM_GRAPHS), dim3(256), 0, stream, O3, start, out);
}